// Round 6
// baseline (13790.593 us; speedup 1.0000x reference)
//
#include <hip/hip_runtime.h>

// Recurrent spiking LIF network: T=64, B=32, NE=4096, NI=1024, N=5120.
// Spikes exactly {0,1}; fp64 accumulation => spike-identical to the fp64
// numpy reference (verified rounds 2/5: absmax 0.0).
//
// Round-6: j-in-lane dense fp64 matvec, no LDS.
//  - wave = 16 n-lanes x 4 j-lanes; lane accumulates 2 n x 8 j in regs.
//  - spikes: ONE double4 global load per (lane-j, k-quad) serves 8 FMAs;
//    address depends on lane>>4 => divergent => stays a vector VMEM load
//    (no round-3 SMEM scalarization). Spike array 1.25 MB = L2-resident.
//  - weights per-lane-row float4 streams (L1-friendly), cvt 8x per quad
//    amortized over 64 FMAs (~11% tax).
//  - __launch_bounds__(256,4) caps VGPR at 128 => 4 waves/SIMD.

#define NE 4096
#define NI 1024
#define NN 5120
#define BB 32

typedef double double4_t __attribute__((ext_vector_type(4)));

// ---------------- matvec partial kernel ----------------
// grid: (NN/128, G), block 256 (4 waves). Wave covers 32 n x all 32 j over
// KR = NN/G sources. Lane (j4 = lane>>4, n16 = lane&15) owns
// n in {n0+n16, n0+n16+16}, j in {j4, j4+4, ..., j4+28}.
template <int KR>
__global__ __launch_bounds__(256, 4) void mv_kernel(
    const float* __restrict__ W_ee, const float* __restrict__ W_ei,
    const float* __restrict__ W_ie, const float* __restrict__ W_ii,
    const double* __restrict__ sd,   // [BB][NN] spikes fp64 (0.0/1.0)
    double* __restrict__ partial)    // [G][BB][NN]
{
    const int lane = threadIdx.x & 63;
    const int wave = threadIdx.x >> 6;
    const int j4   = lane >> 4;                 // 0..3
    const int n16  = lane & 15;
    const int n0   = blockIdx.x * 128 + wave * 32;
    const int kb   = blockIdx.y * KR;

    const int nA = n0 + n16;        // first owned neuron
    const int nB = nA + 16;         // second owned neuron

    const float* __restrict__ rEA = (nA < NE) ? (W_ee + (size_t)nA * NE)
                                              : (W_ei + (size_t)(nA - NE) * NE);
    const float* __restrict__ rEB = (nB < NE) ? (W_ee + (size_t)nB * NE)
                                              : (W_ei + (size_t)(nB - NE) * NE);
    const float* __restrict__ rIA = (nA < NE) ? (W_ie + (size_t)nA * NI)
                                              : (W_ii + (size_t)(nA - NE) * NI);
    const float* __restrict__ rIB = (nB < NE) ? (W_ie + (size_t)nB * NI)
                                              : (W_ii + (size_t)(nB - NE) * NI);

    const double* __restrict__ sdj = sd + (size_t)j4 * NN;  // lane's j base

    double accA[8], accB[8];
#pragma unroll
    for (int jr = 0; jr < 8; ++jr) { accA[jr] = 0.0; accB[jr] = 0.0; }

    int aEnd = NE - kb;                   // E/I source boundary inside range
    if (aEnd < 0) aEnd = 0;
    if (aEnd > KR) aEnd = KR;             // always a multiple of 4

    // ---- excitatory sources ----
#pragma unroll 2
    for (int kk = 0; kk < aEnd; kk += 4) {
        const int k = kb + kk;
        const float4 wa = *reinterpret_cast<const float4*>(rEA + k);
        const float4 wb = *reinterpret_cast<const float4*>(rEB + k);
        const double wa0 = (double)wa.x, wa1 = (double)wa.y,
                     wa2 = (double)wa.z, wa3 = (double)wa.w;
        const double wb0 = (double)wb.x, wb1 = (double)wb.y,
                     wb2 = (double)wb.z, wb3 = (double)wb.w;
#pragma unroll
        for (int jr = 0; jr < 8; ++jr) {
            const double4_t s = *reinterpret_cast<const double4_t*>(
                sdj + (size_t)jr * 4 * NN + k);
            accA[jr] += wa0 * s.x + wa1 * s.y + wa2 * s.z + wa3 * s.w;
            accB[jr] += wb0 * s.x + wb1 * s.y + wb2 * s.z + wb3 * s.w;
        }
    }
    // ---- inhibitory sources ----
#pragma unroll 2
    for (int kk = aEnd; kk < KR; kk += 4) {
        const int k = kb + kk;            // >= NE here
        const float4 wa = *reinterpret_cast<const float4*>(rIA + (k - NE));
        const float4 wb = *reinterpret_cast<const float4*>(rIB + (k - NE));
        const double wa0 = (double)wa.x, wa1 = (double)wa.y,
                     wa2 = (double)wa.z, wa3 = (double)wa.w;
        const double wb0 = (double)wb.x, wb1 = (double)wb.y,
                     wb2 = (double)wb.z, wb3 = (double)wb.w;
#pragma unroll
        for (int jr = 0; jr < 8; ++jr) {
            const double4_t s = *reinterpret_cast<const double4_t*>(
                sdj + (size_t)jr * 4 * NN + k);
            accA[jr] += wa0 * s.x + wa1 * s.y + wa2 * s.z + wa3 * s.w;
            accB[jr] += wb0 * s.x + wb1 * s.y + wb2 * s.z + wb3 * s.w;
        }
    }

#pragma unroll
    for (int jr = 0; jr < 8; ++jr) {
        const size_t base = ((size_t)blockIdx.y * BB + (j4 + 4 * jr)) * NN;
        partial[base + nA] = accA[jr];
        partial[base + nB] = accB[jr];
    }
}

// ---------------- LIF update kernel ----------------
template <int G>
__global__ __launch_bounds__(256) void upd_kernel(
    const float* __restrict__ ext_exc,   // [T][BB][NE]
    const float* __restrict__ ext_inh,   // [T][BB][NI]
    const double* __restrict__ partial,  // [G][BB][NN]
    double* __restrict__ v,              // [BB][NN]
    double* __restrict__ sd,             // [BB][NN] fp64 spikes
    float* __restrict__ out,             // [T][BB][NN]
    int t)
{
    const int idx = blockIdx.x * 256 + threadIdx.x;   // < BB*NN
    const int b = idx / NN;
    const int n = idx - b * NN;

    const float ext = (n < NE)
        ? ext_exc[((size_t)t * BB + b) * NE + n]
        : ext_inh[((size_t)t * BB + b) * NI + (n - NE)];

    double acc = (double)ext;
#pragma unroll
    for (int g = 0; g < G; ++g)
        acc += partial[((size_t)g * BB + b) * NN + n];

    const double vv = v[idx] * 0.9 + acc;
    const double sp = (vv > 1.0) ? 1.0 : 0.0;
    out[(size_t)t * BB * NN + idx] = (float)sp;
    v[idx] = vv * (1.0 - sp);
    sd[idx] = sp;
}

extern "C" void kernel_launch(void* const* d_in, const int* in_sizes, int n_in,
                              void* d_out, int out_size, void* d_ws, size_t ws_size,
                              hipStream_t stream) {
    const float* ext_exc = (const float*)d_in[0];
    const float* ext_inh = (const float*)d_in[1];
    const float* W_ee = (const float*)d_in[2];
    const float* W_ei = (const float*)d_in[3];
    const float* W_ie = (const float*)d_in[4];
    const float* W_ii = (const float*)d_in[5];
    float* out = (float*)d_out;

    const int T = in_sizes[0] / (BB * NE);   // 64

    const size_t SN = (size_t)BB * NN;       // 163840
    double* v = (double*)d_ws;               // [BB][NN]
    double* sd = v + SN;                     // [BB][NN]
    double* partial = sd + SN;               // [G][BB][NN]
    const size_t stateBytes = 2 * SN * sizeof(double);   // ~2.6 MB

    // largest k-split G whose fp64 partial fits the workspace
    // (round 2/5 WRITE_SIZE=41.9MB proves G=32 path fits on this harness)
    int G = 32;
    while (G > 8 && stateBytes + (size_t)G * SN * sizeof(double) > ws_size) G >>= 1;

    hipMemsetAsync(d_ws, 0, stateBytes, stream);   // v = 0, spikes = 0

    for (int t = 0; t < T; ++t) {
        switch (G) {
            case 32:
                mv_kernel<160> <<<dim3(NN/128, 32), 256, 0, stream>>>(W_ee, W_ei, W_ie, W_ii, sd, partial);
                upd_kernel<32><<<(int)(SN/256), 256, 0, stream>>>(ext_exc, ext_inh, partial, v, sd, out, t);
                break;
            case 16:
                mv_kernel<320> <<<dim3(NN/128, 16), 256, 0, stream>>>(W_ee, W_ei, W_ie, W_ii, sd, partial);
                upd_kernel<16><<<(int)(SN/256), 256, 0, stream>>>(ext_exc, ext_inh, partial, v, sd, out, t);
                break;
            default:
                mv_kernel<640> <<<dim3(NN/128, 8), 256, 0, stream>>>(W_ee, W_ei, W_ie, W_ii, sd, partial);
                upd_kernel<8> <<<(int)(SN/256), 256, 0, stream>>>(ext_exc, ext_inh, partial, v, sd, out, t);
                break;
        }
    }
}

// Round 7
// 11492.353 us; speedup vs baseline: 1.2000x; 1.2000x over previous
//
#include <hip/hip_runtime.h>

// Recurrent spiking LIF network: T=64, B=32, NE=4096, NI=1024, N=5120.
// Spikes exactly {0,1}; fp64 accumulation => spike-identical to the fp64
// numpy reference (verified rounds 2/5/6: absmax 0.0).
//
// Round-7: refined round-2 structure (the best measured: 105us/step).
//  - G=16 k-split (partial traffic halved vs G=32: 21MB w + 21MB r).
//  - batch-split z=2: block covers 16 of 32 batches -> grid stays 640
//    blocks (2.5/CU) without raising partial bytes.
//  - spikes fp32 staged in LDS ONCE per block (CHUNK = KR = 320, one
//    __syncthreads) -> no per-wave global spike refetch (round-6 lesson).
//  - inner loop: per k-quad: 1 weight float4 + 16 broadcast ds_read_b128
//    + 64 cvt + 64 fma; 16 independent fp64 acc chains.

#define NE 4096
#define NI 1024
#define NN 5120
#define BB 32
#define JH 16        // batches per block (j-half)
#define CHUNK 320    // k-elements staged per LDS pass: 16*320*4 = 20 KB

// ---------------- matvec partial kernel ----------------
// grid: (NN/256, G, 2), block 256. Thread owns target neuron n,
// accumulates acc[JH] over KR = NN/G sources for its j-half.
template <int KR>
__global__ __launch_bounds__(256, 4) void mv_kernel(
    const float* __restrict__ W_ee, const float* __restrict__ W_ei,
    const float* __restrict__ W_ie, const float* __restrict__ W_ii,
    const float* __restrict__ sd,    // [BB][NN] spikes fp32 (0.0/1.0)
    double* __restrict__ partial)    // [G][BB][NN]
{
    __shared__ float s_l[JH][CHUNK];
    const int t = threadIdx.x;
    const int n = blockIdx.x * 256 + t;        // 0..NN-1
    const int jh = blockIdx.z * JH;            // batch base
    const int kb0 = blockIdx.y * KR;

    double acc[JH];
#pragma unroll
    for (int j = 0; j < JH; ++j) acc[j] = 0.0;

    const bool isE = (n < NE);
    const int nr = isE ? n : n - NE;
    const float* __restrict__ rowA = isE ? (W_ee + (size_t)nr * NE) : (W_ei + (size_t)nr * NE);
    const float* __restrict__ rowB = isE ? (W_ie + (size_t)nr * NI) : (W_ii + (size_t)nr * NI);

    for (int pass = 0; pass < KR / CHUNK; ++pass) {
        const int kb = kb0 + pass * CHUNK;

        if (pass) __syncthreads();
        for (int ii = t; ii < JH * CHUNK; ii += 256) {
            const int j = ii / CHUNK;
            const int kk = ii - j * CHUNK;
            s_l[j][kk] = sd[(size_t)(jh + j) * NN + kb + kk];
        }
        __syncthreads();

        int aEnd = NE - kb;                    // E/I source boundary
        if (aEnd < 0) aEnd = 0;
        if (aEnd > CHUNK) aEnd = CHUNK;        // multiple of 4 always

        for (int kk = 0; kk < aEnd; kk += 4) {
            const float4 w = *reinterpret_cast<const float4*>(rowA + kb + kk);
            const double w0 = (double)w.x, w1 = (double)w.y,
                         w2 = (double)w.z, w3 = (double)w.w;
#pragma unroll
            for (int j = 0; j < JH; ++j) {
                const float4 sv = *reinterpret_cast<const float4*>(&s_l[j][kk]);
                acc[j] += w0 * (double)sv.x + w1 * (double)sv.y
                        + w2 * (double)sv.z + w3 * (double)sv.w;
            }
        }
        for (int kk = aEnd; kk < CHUNK; kk += 4) {
            const float4 w = *reinterpret_cast<const float4*>(rowB + (kb + kk - NE));
            const double w0 = (double)w.x, w1 = (double)w.y,
                         w2 = (double)w.z, w3 = (double)w.w;
#pragma unroll
            for (int j = 0; j < JH; ++j) {
                const float4 sv = *reinterpret_cast<const float4*>(&s_l[j][kk]);
                acc[j] += w0 * (double)sv.x + w1 * (double)sv.y
                        + w2 * (double)sv.z + w3 * (double)sv.w;
            }
        }
    }

#pragma unroll
    for (int j = 0; j < JH; ++j)
        partial[((size_t)blockIdx.y * BB + jh + j) * NN + n] = acc[j];
}

// ---------------- LIF update kernel ----------------
template <int G>
__global__ __launch_bounds__(256) void upd_kernel(
    const float* __restrict__ ext_exc,   // [T][BB][NE]
    const float* __restrict__ ext_inh,   // [T][BB][NI]
    const double* __restrict__ partial,  // [G][BB][NN]
    double* __restrict__ v,              // [BB][NN]
    float* __restrict__ sd,              // [BB][NN] fp32 spikes
    float* __restrict__ out,             // [T][BB][NN]
    int t)
{
    const int idx = blockIdx.x * 256 + threadIdx.x;   // < BB*NN
    const int b = idx / NN;
    const int n = idx - b * NN;

    const float ext = (n < NE)
        ? ext_exc[((size_t)t * BB + b) * NE + n]
        : ext_inh[((size_t)t * BB + b) * NI + (n - NE)];

    double acc = (double)ext;
#pragma unroll
    for (int g = 0; g < G; ++g)
        acc += partial[((size_t)g * BB + b) * NN + n];

    const double vv = v[idx] * 0.9 + acc;
    const double sp = (vv > 1.0) ? 1.0 : 0.0;
    out[(size_t)t * BB * NN + idx] = (float)sp;
    v[idx] = vv * (1.0 - sp);
    sd[idx] = (float)sp;
}

extern "C" void kernel_launch(void* const* d_in, const int* in_sizes, int n_in,
                              void* d_out, int out_size, void* d_ws, size_t ws_size,
                              hipStream_t stream) {
    const float* ext_exc = (const float*)d_in[0];
    const float* ext_inh = (const float*)d_in[1];
    const float* W_ee = (const float*)d_in[2];
    const float* W_ei = (const float*)d_in[3];
    const float* W_ie = (const float*)d_in[4];
    const float* W_ii = (const float*)d_in[5];
    float* out = (float*)d_out;

    const int T = in_sizes[0] / (BB * NE);   // 64

    const size_t SN = (size_t)BB * NN;       // 163840
    double* v = (double*)d_ws;               // [BB][NN] fp64
    float* sd = (float*)(v + SN);            // [BB][NN] fp32
    double* partial = (double*)(sd + SN);    // [G][BB][NN] fp64 (8B-aligned)
    const size_t stateBytes = SN * 12;       // v + sd, ~2.0 MB

    // largest k-split G whose fp64 partial fits (round 5 proved 44MB fits)
    int G = 16;
    while (G > 4 && stateBytes + (size_t)G * SN * sizeof(double) > ws_size) G >>= 1;

    hipMemsetAsync(d_ws, 0, stateBytes, stream);   // v = 0, spikes = 0

    for (int t = 0; t < T; ++t) {
        switch (G) {
            case 16:
                mv_kernel<320> <<<dim3(NN/256, 16, 2), 256, 0, stream>>>(W_ee, W_ei, W_ie, W_ii, sd, partial);
                upd_kernel<16><<<(int)(SN/256), 256, 0, stream>>>(ext_exc, ext_inh, partial, v, sd, out, t);
                break;
            case 8:
                mv_kernel<640> <<<dim3(NN/256, 8, 2), 256, 0, stream>>>(W_ee, W_ei, W_ie, W_ii, sd, partial);
                upd_kernel<8> <<<(int)(SN/256), 256, 0, stream>>>(ext_exc, ext_inh, partial, v, sd, out, t);
                break;
            default:
                mv_kernel<1280><<<dim3(NN/256, 4, 2), 256, 0, stream>>>(W_ee, W_ei, W_ie, W_ii, sd, partial);
                upd_kernel<4> <<<(int)(SN/256), 256, 0, stream>>>(ext_exc, ext_inh, partial, v, sd, out, t);
                break;
        }
    }
}